// Round 13
// baseline (4177.869 us; speedup 1.0000x reference)
//
#include <hip/hip_runtime.h>
#include <hip/hip_bf16.h>
#include <stdint.h>

typedef __attribute__((ext_vector_type(8))) short bf16x8;
typedef __attribute__((ext_vector_type(4))) float f32x4;
typedef __attribute__((ext_vector_type(8))) unsigned short u16x8;

#define BM 512
#define BN 256
#define BKT 32
#define ABYTES (BM * BKT * 2)        // 32768
#define BBYTES (BN * BKT * 2)        // 16384
#define BUFBYTES (ABYTES + BBYTES)   // 49152; 2 buffers = 96 KB LDS

// ---- MXFP8 quant-dequant to bf16 (verified r1/r5-r12: absmax 0.03125) ------
__device__ __forceinline__ float mx_qd_elem(float x, int e) {
    float xs = ldexpf(x, -e);
    xs = fminf(448.f, fmaxf(-448.f, xs));
    float a = fabsf(xs);
    float r;
    if (a < 0.015625f) {                  // below 2^-6: e4m3 subnormal, quantum 2^-9
        r = ldexpf(rintf(ldexpf(a, 9)), -9);
    } else {                              // normal: quantum 2^(E-3)
        int E = (int)((__float_as_uint(a) >> 23) & 0xFF) - 127;
        r = ldexpf(rintf(ldexpf(a, 3 - E)), E - 3);
    }
    r = copysignf(r, xs);
    return ldexpf(r, e);
}

__global__ __launch_bounds__(256) void mx_quant_bf16(
    const float* __restrict__ in, uint16_t* __restrict__ out, int nblk) {
    int t = blockIdx.x * 256 + threadIdx.x;
    if (t >= nblk) return;
    const float4* p = (const float4*)(in + (size_t)t * 32);
    float v[32];
#pragma unroll
    for (int i = 0; i < 8; ++i) {
        float4 fv = p[i];
        v[4 * i + 0] = fv.x; v[4 * i + 1] = fv.y;
        v[4 * i + 2] = fv.z; v[4 * i + 3] = fv.w;
    }
    float amax = 0.f;
#pragma unroll
    for (int i = 0; i < 32; ++i) amax = fmaxf(amax, fabsf(v[i]));
    amax = fmaxf(amax, 1.17549435e-38f);
    int e = (int)((__float_as_uint(amax) >> 23) & 0xFF) - 127 - 8;

    unsigned short res[32];
#pragma unroll
    for (int i = 0; i < 32; ++i) {
        float d = mx_qd_elem(v[i], e);
        res[i] = (unsigned short)(__float_as_uint(d) >> 16);
    }
    u16x8* o = (u16x8*)(out + (size_t)t * 32);
#pragma unroll
    for (int j = 0; j < 4; ++j) {
        u16x8 pack;
#pragma unroll
        for (int i = 0; i < 8; ++i) pack[i] = res[8 * j + i];
        o[j] = pack;
    }
}

// ---- 512x256 chunk-pipelined bf16 GEMM: C = A * B^T + bias -----------------
// Staged traffic = M*N*K*2*(1/BM+1/BN): 512x256 cuts it 25% vs 256x256
// (4.3 -> 3.2 GB/dispatch) -- the r5-r12 invariant says we're bound by
// per-CU staging rate (~14 B/cyc), so bytes ARE time.
// 8 waves (2M x 4N), per-wave 256x64, acc[16][4]; BKT=32; 2-buf (96 KB);
// r8 chunk schedule (4 A-chunks, counted lgkm); r10 slot-swizzle (0 confl);
// r12 column-chunked snake XCD swizzle (B-panel L2-resident).
#define GLOAD(srcp, ldsoff)                                                     \
    __builtin_amdgcn_global_load_lds(                                           \
        (const __attribute__((address_space(1))) void*)(srcp),                  \
        (__attribute__((address_space(3))) void*)&lds[ldsoff], 16, 0, 0)

__global__ __launch_bounds__(512, 2) void gemm_t5_bf16(
    const uint16_t* __restrict__ A, const uint16_t* __restrict__ B,
    const float* __restrict__ bias, float* __restrict__ C,
    int Nrows, int K, int O) {
    __shared__ __align__(16) uint8_t lds[2 * BUFBYTES];   // 96 KB

    const int tid  = threadIdx.x;
    const int lane = tid & 63;
    const int w    = tid >> 6;
    const int f    = lane & 15, g = lane >> 4;
    const int wm   = w >> 2,    wn = w & 3;     // 2M x 4N; per-wave 256x64

    // column-chunked snake XCD swizzle (nwg = 512, bijective)
    const int flat = blockIdx.y * gridDim.x + blockIdx.x;   // 0..511
    const int xcd  = flat & 7;
    const int loc  = flat >> 3;                 // 0..63 within XCD
    const int bxl  = loc >> 5;                  // column 0/1 within XCD band
    const int byl  = loc & 31;
    const int by   = bxl ? (31 - byl) : byl;    // snake
    const int bx   = xcd * 2 + bxl;
    const int rowBase = by * BM, colBase = bx * BN;

    // staging: round = 128 rows x 64 B (8 KB); thread covers 16 B.
    // linear LDS dest (rule 21); SOURCE slot swizzled (r10-verified involution).
    const int srow = tid >> 2;                               // 0..127
    const int ssc  = ((tid & 3) ^ ((srow >> 1) & 3)) * 16;   // source byte col
    const int sld  = tid * 16;
    const size_t K2 = (size_t)K * 2;
    const uint8_t* gAr[4]; const uint8_t* gBr[2];
#pragma unroll
    for (int r = 0; r < 4; ++r)
        gAr[r] = (const uint8_t*)A + (size_t)(rowBase + r * 128 + srow) * K2 + ssc;
#pragma unroll
    for (int r = 0; r < 2; ++r)
        gBr[r] = (const uint8_t*)B + (size_t)(colBase + r * 128 + srow) * K2 + ssc;
#define STAGE(t) do {                                                           \
        const int _buf = ((t) & 1) * BUFBYTES;                                  \
        const size_t _kb = (size_t)(t) * (BKT * 2);                             \
        _Pragma("unroll")                                                       \
        for (int _i = 0; _i < 4; ++_i)                                          \
            GLOAD(gAr[_i] + _kb, _buf + _i * 8192 + sld);                       \
        _Pragma("unroll")                                                       \
        for (int _i = 0; _i < 2; ++_i)                                          \
            GLOAD(gBr[_i] + _kb, _buf + ABYTES + _i * 8192 + sld);              \
    } while (0)

    // frag-read offsets: row r (64 B), k-slot g -> r*64 + (g ^ ((r>>1)&3))*16
    int aoff[16], boff[4];
#pragma unroll
    for (int m = 0; m < 16; ++m) {
        int r = wm * 256 + m * 16 + f;
        aoff[m] = r * 64 + ((g ^ ((r >> 1) & 3)) * 16);
    }
#pragma unroll
    for (int n = 0; n < 4; ++n) {
        int r = wn * 64 + n * 16 + f;
        boff[n] = ABYTES + r * 64 + ((g ^ ((r >> 1) & 3)) * 16);
    }

    f32x4 acc[16][4];
#pragma unroll
    for (int m = 0; m < 16; ++m)
#pragma unroll
        for (int n = 0; n < 4; ++n)
#pragma unroll
            for (int j = 0; j < 4; ++j) acc[m][n][j] = 0.f;

    const int nt = K / BKT;   // 128

#define WAITL(N) do {                                                           \
        asm volatile("s_waitcnt lgkmcnt(" #N ")" ::: "memory");                 \
        __builtin_amdgcn_sched_barrier(0);                                      \
    } while (0)
#define MFMA_C(MB, AF, BF) do {                                                 \
        __builtin_amdgcn_s_setprio(1);                                          \
        _Pragma("unroll") for (int _m = 0; _m < 4; ++_m)                        \
        _Pragma("unroll") for (int _n = 0; _n < 4; ++_n)                        \
            acc[(MB) + _m][_n] = __builtin_amdgcn_mfma_f32_16x16x32_bf16(       \
                AF[_m], BF[_n], acc[(MB) + _m][_n], 0, 0, 0);                   \
        __builtin_amdgcn_s_setprio(0);                                          \
    } while (0)

    // prologue: stage tile 0, drain, publish
    STAGE(0);
    asm volatile("s_waitcnt vmcnt(0)" ::: "memory");
    __builtin_amdgcn_sched_barrier(0);
    __builtin_amdgcn_s_barrier();
    __builtin_amdgcn_sched_barrier(0);

    for (int t = 0; t < nt; ++t) {
        const int bb = (t & 1) * BUFBYTES;
        const bool pf = (t + 1) < nt;
        bf16x8 bA[4], a0[4], a1[4], a2[4], a3[4];

        // c0 (8 reads): B n0-3 + A m0-3        [lgkm out: 8]
#pragma unroll
        for (int n = 0; n < 4; ++n) bA[n] = *(const bf16x8*)&lds[bb + boff[n]];
#pragma unroll
        for (int m = 0; m < 4; ++m) a0[m] = *(const bf16x8*)&lds[bb + aoff[m]];
        // c1 (4 reads): A m4-7                 [out: 12]
#pragma unroll
        for (int m = 0; m < 4; ++m) a1[m] = *(const bf16x8*)&lds[bb + aoff[4 + m]];
        if (pf) STAGE(t + 1);            // 6 gloads; issue overlaps c0 drain
        WAITL(4);                        // c0 done (c1 outstanding)
        // c2 (4 reads): A m8-11                [out: 8]
#pragma unroll
        for (int m = 0; m < 4; ++m) a2[m] = *(const bf16x8*)&lds[bb + aoff[8 + m]];
        MFMA_C(0, a0, bA);               // cluster 1; c1+c2 drain under it
        WAITL(4);                        // c1 done (c2 outstanding)
        // c3 (4 reads): A m12-15               [out: 8]
#pragma unroll
        for (int m = 0; m < 4; ++m) a3[m] = *(const bf16x8*)&lds[bb + aoff[12 + m]];
        MFMA_C(4, a1, bA);               // cluster 2; c3 drains under it
        WAITL(4);                        // c2 done (c3 outstanding)
        MFMA_C(8, a2, bA);               // cluster 3
        WAITL(0);                        // c3 done
        MFMA_C(12, a3, bA);              // cluster 4
        // publish tile t+1 and release buffers
        asm volatile("s_waitcnt vmcnt(0)" ::: "memory");
        __builtin_amdgcn_sched_barrier(0);
        __builtin_amdgcn_s_barrier();
        __builtin_amdgcn_sched_barrier(0);
    }
#undef STAGE
#undef WAITL
#undef MFMA_C

    // epilogue: C/D layout col=lane&15, row=(lane>>4)*4+j (r1/r5-r12 verified)
    const int qr = g * 4;
#pragma unroll
    for (int n = 0; n < 4; ++n) {
        int col = colBase + wn * 64 + n * 16 + f;
        float bv = bias[col];
#pragma unroll
        for (int m = 0; m < 16; ++m) {
            int r0 = rowBase + wm * 256 + m * 16 + qr;
#pragma unroll
            for (int j = 0; j < 4; ++j)
                C[(size_t)(r0 + j) * O + col] = acc[m][n][j] + bv;
        }
    }
}

extern "C" void kernel_launch(void* const* d_in, const int* in_sizes, int n_in,
                              void* d_out, int out_size, void* d_ws, size_t ws_size,
                              hipStream_t stream) {
    const float* x    = (const float*)d_in[0];
    const float* wgt  = (const float*)d_in[1];
    const float* bias = (const float*)d_in[2];
    float* out = (float*)d_out;

    const int D_OUT = in_sizes[2];             // 4096
    const int D_IN  = in_sizes[1] / D_OUT;     // 4096
    const int NROWS = in_sizes[0] / D_IN;      // 16384

    uint16_t* xq = (uint16_t*)d_ws;                     // 128 MB
    uint16_t* wq = xq + (size_t)NROWS * D_IN;           //  32 MB

    int nblkx = NROWS * (D_IN / 32);
    int nblkw = D_OUT * (D_IN / 32);
    mx_quant_bf16<<<dim3((nblkx + 255) / 256), dim3(256), 0, stream>>>(x, xq, nblkx);
    mx_quant_bf16<<<dim3((nblkw + 255) / 256), dim3(256), 0, stream>>>(wgt, wq, nblkw);

    dim3 grid(D_OUT / BN, NROWS / BM);   // (16, 32) = 512 blocks
    gemm_t5_bf16<<<grid, dim3(512), 0, stream>>>(xq, wq, bias, out,
                                                 NROWS, D_IN, D_OUT);
}

// Round 14
// 2724.382 us; speedup vs baseline: 1.5335x; 1.5335x over previous
//
#include <hip/hip_runtime.h>
#include <hip/hip_bf16.h>
#include <stdint.h>

typedef __attribute__((ext_vector_type(8))) short bf16x8;
typedef __attribute__((ext_vector_type(4))) float f32x4;
typedef __attribute__((ext_vector_type(2))) float f32x2;
typedef __attribute__((ext_vector_type(4))) int i32x4;

#define BM 256
#define BN 256
#define BKT 64
#define ABYTES (BM * BKT)            // fp8: 16384
#define BBYTES (BN * BKT)            // 16384
#define BUFBYTES (ABYTES + BBYTES)   // 32768; 2 buffers = 64 KB LDS

// ---------------- fp8 e4m3 encode (mirrors verified mx_qd_elem math) --------
__device__ __forceinline__ uint8_t enc_e4m3(float x, int e) {
    float xs = ldexpf(x, -e);
    xs = fminf(448.f, fmaxf(-448.f, xs));
    float a = fabsf(xs);
    uint32_t sgn = (__float_as_uint(xs) >> 31) << 7;
    uint32_t mag;
    if (a < 0.015625f) {                       // < 2^-6: subnormal, quantum 2^-9
        mag = (uint32_t)(int)rintf(ldexpf(a, 9));   // 0..8 (8 rolls into 0x08 = 2^-6)
    } else {                                   // normal: quantum 2^(E-3)
        int E = (int)((__float_as_uint(a) >> 23) & 0xFF) - 127;
        float q = ldexpf(rintf(ldexpf(a, 3 - E)), E - 3);   // RNE on grid
        uint32_t qb = __float_as_uint(q);
        int E2 = (int)((qb >> 23) & 0xFF) - 127;            // mantissa may carry
        mag = ((uint32_t)(E2 + 7) << 3) | ((qb >> 20) & 7);
    }
    return (uint8_t)(sgn | mag);
}

// one thread = one MX block (32 contiguous fp32). Writes e4m3 bytes (row-major
// [row][K]) + e8m0 scale byte sout[t] (row-major [row][K/32], t is linear).
__global__ __launch_bounds__(256) void mx_quant_fp8(
    const float* __restrict__ in, uint8_t* __restrict__ qout,
    uint8_t* __restrict__ sout, int nblk) {
    int t = blockIdx.x * 256 + threadIdx.x;
    if (t >= nblk) return;
    const float4* p = (const float4*)(in + (size_t)t * 32);
    float v[32];
#pragma unroll
    for (int i = 0; i < 8; ++i) {
        float4 fv = p[i];
        v[4 * i + 0] = fv.x; v[4 * i + 1] = fv.y;
        v[4 * i + 2] = fv.z; v[4 * i + 3] = fv.w;
    }
    float amax = 0.f;
#pragma unroll
    for (int i = 0; i < 32; ++i) amax = fmaxf(amax, fabsf(v[i]));
    amax = fmaxf(amax, 1.17549435e-38f);
    int e = (int)((__float_as_uint(amax) >> 23) & 0xFF) - 127 - 8;  // floor(log2)-8
    int E = e + 127;                       // decode multiplier = 2^(E-127) (ours)
    E = E < 1 ? 1 : (E > 254 ? 254 : E);
    sout[t] = (uint8_t)E;

    uint8_t b[32];
#pragma unroll
    for (int i = 0; i < 32; ++i) b[i] = enc_e4m3(v[i], e);
    uint4 w0, w1;
    uint32_t* pw = (uint32_t*)&w0;
#pragma unroll
    for (int j = 0; j < 4; ++j)
        pw[j] = (uint32_t)b[4*j] | ((uint32_t)b[4*j+1] << 8) |
                ((uint32_t)b[4*j+2] << 16) | ((uint32_t)b[4*j+3] << 24);
    pw = (uint32_t*)&w1;
#pragma unroll
    for (int j = 0; j < 4; ++j)
        pw[j] = (uint32_t)b[16+4*j] | ((uint32_t)b[16+4*j+1] << 8) |
                ((uint32_t)b[16+4*j+2] << 16) | ((uint32_t)b[16+4*j+3] << 24);
    uint4* o = (uint4*)(qout + (size_t)t * 32);
    o[0] = w0; o[1] = w1;
}

// ---------------- fp8 -> f32 pair decode (HW cvt preferred) -----------------
#if __has_builtin(__builtin_amdgcn_cvt_pk_f32_fp8)
#define CVTPK(w, hi) __builtin_amdgcn_cvt_pk_f32_fp8((int)(w), hi)
#else
__device__ __forceinline__ f32x2 CVTPK_sw(uint32_t w, bool hi) {
    f32x2 r;
#pragma unroll
    for (int j = 0; j < 2; ++j) {
        uint32_t b = (w >> ((hi ? 2 : 0) + j) * 8) & 0xFF;
        uint32_t s = (b >> 7) << 31;
        uint32_t ex = (b >> 3) & 15, mn = b & 7;
        float v = ex ? __uint_as_float(((ex - 7 + 127) << 23) | (mn << 20))
                     : ldexpf((float)mn, -9);
        r[j] = __uint_as_float(s | __float_as_uint(v));
    }
    return r;
}
#define CVTPK(w, hi) CVTPK_sw((w), hi)
#endif

// expand 8 fp8 bytes (uint2) * 2^(SB-127) -> bf16x8. Exact at every step.
#define EXPAND(FR, RAW, SB) do {                                                \
        float _s = __uint_as_float((uint32_t)(SB) << 23);                       \
        f32x2 _p0 = CVTPK((RAW).x, false), _p1 = CVTPK((RAW).x, true);          \
        f32x2 _p2 = CVTPK((RAW).y, false), _p3 = CVTPK((RAW).y, true);          \
        i32x4 _d;                                                               \
        _d[0] = (int)__builtin_amdgcn_perm(__float_as_uint(_p0[1] * _s),        \
                    __float_as_uint(_p0[0] * _s), 0x07060302);                  \
        _d[1] = (int)__builtin_amdgcn_perm(__float_as_uint(_p1[1] * _s),        \
                    __float_as_uint(_p1[0] * _s), 0x07060302);                  \
        _d[2] = (int)__builtin_amdgcn_perm(__float_as_uint(_p2[1] * _s),        \
                    __float_as_uint(_p2[0] * _s), 0x07060302);                  \
        _d[3] = (int)__builtin_amdgcn_perm(__float_as_uint(_p3[1] * _s),        \
                    __float_as_uint(_p3[0] * _s), 0x07060302);                  \
        FR = *(const bf16x8*)&_d;                                               \
    } while (0)

// ---------------- 256x256 fp8-compressed-LDS GEMM: C = A * B^T + bias -------
// r12 skeleton; LDS holds e4m3 (half the staged bytes); frags = ds_read_b64 ->
// exact VALU expansion to bf16 -> verified 16x16x32 bf16 MFMA. Scales (e8m0)
// global->VGPR, prefetched depth-1. r10 slot-swizzle (64B rows); snake XCD.
#define GLOAD(srcp, ldsoff)                                                     \
    __builtin_amdgcn_global_load_lds(                                           \
        (const __attribute__((address_space(1))) void*)(srcp),                  \
        (__attribute__((address_space(3))) void*)&lds[ldsoff], 16, 0, 0)

__global__ __launch_bounds__(512, 2) void gemm_fp8c_bf16(
    const uint8_t* __restrict__ A, const uint8_t* __restrict__ B,
    const uint8_t* __restrict__ As, const uint8_t* __restrict__ Bs,
    const float* __restrict__ bias, float* __restrict__ C,
    int Nrows, int K, int O) {
    __shared__ __align__(16) uint8_t lds[2 * BUFBYTES];   // 64 KB

    const int tid  = threadIdx.x;
    const int lane = tid & 63;
    const int w    = tid >> 6;
    const int f    = lane & 15, g = lane >> 4;
    const int wm   = w >> 2,    wn = w & 3;     // 2M x 4N

    // r12 column-chunked snake XCD swizzle (nwg=1024, bijective)
    const int flat = blockIdx.y * gridDim.x + blockIdx.x;
    const int xcd  = flat & 7;
    const int loc  = flat >> 3;
    const int bxl  = loc >> 6;
    const int byl  = loc & 63;
    const int by   = bxl ? (63 - byl) : byl;
    const int bx   = xcd * 2 + bxl;
    const int rowBase = by * BM, colBase = bx * BN;

    // staging: round = 128 rows x 64 B; thread covers 16 B (r10-verified).
    const int srow = tid >> 2;
    const int ssc  = ((tid & 3) ^ ((srow >> 1) & 3)) * 16;
    const int sld  = tid * 16;
    const uint8_t* gA0 = A + (size_t)(rowBase + srow) * K + ssc;
    const uint8_t* gA1 = A + (size_t)(rowBase + 128 + srow) * K + ssc;
    const uint8_t* gB0 = B + (size_t)(colBase + srow) * K + ssc;
    const uint8_t* gB1 = B + (size_t)(colBase + 128 + srow) * K + ssc;
#define STAGE(t) do {                                                           \
        const int _buf = ((t) & 1) * BUFBYTES;                                  \
        const size_t _kb = (size_t)(t) * BKT;                                   \
        GLOAD(gA0 + _kb, _buf + sld);                                           \
        GLOAD(gA1 + _kb, _buf + 8192 + sld);                                    \
        GLOAD(gB0 + _kb, _buf + ABYTES + sld);                                  \
        GLOAD(gB1 + _kb, _buf + ABYTES + 8192 + sld);                           \
    } while (0)

    // frag b64 offsets: row r, kk half, K bytes [kk*32+g*8, +8):
    // slot = (kk*2+(g>>1)) ^ ((r>>1)&3); byte = r*64 + slot*16 + (g&1)*8
    int aoffk[8][2], boffk[4][2];
#pragma unroll
    for (int m = 0; m < 8; ++m) {
        int r = wm * 128 + m * 16 + f;
#pragma unroll
        for (int kk = 0; kk < 2; ++kk)
            aoffk[m][kk] = r * 64 + (((kk * 2 + (g >> 1)) ^ ((r >> 1) & 3)) * 16)
                         + (g & 1) * 8;
    }
#pragma unroll
    for (int n = 0; n < 4; ++n) {
        int r = wn * 64 + n * 16 + f;
#pragma unroll
        for (int kk = 0; kk < 2; ++kk)
            boffk[n][kk] = ABYTES + r * 64
                         + (((kk * 2 + (g >> 1)) ^ ((r >> 1) & 3)) * 16)
                         + (g & 1) * 8;
    }

    // per-lane scale address offsets (e8m0, row-major [row][K/32])
    const int KB = K >> 5;
    int sAoff[8], sBoff[4];
#pragma unroll
    for (int m = 0; m < 8; ++m)
        sAoff[m] = (rowBase + wm * 128 + m * 16 + f) * KB;
#pragma unroll
    for (int n = 0; n < 4; ++n)
        sBoff[n] = (colBase + wn * 64 + n * 16 + f) * KB;

    f32x4 acc[8][4];
#pragma unroll
    for (int m = 0; m < 8; ++m)
#pragma unroll
        for (int n = 0; n < 4; ++n)
#pragma unroll
            for (int j = 0; j < 4; ++j) acc[m][n][j] = 0.f;

    const int nt = K / BKT;   // 64 (even)

#define WAITL(N) do {                                                           \
        asm volatile("s_waitcnt lgkmcnt(" #N ")" ::: "memory");                 \
        __builtin_amdgcn_sched_barrier(0);                                      \
    } while (0)
#define MFMA_C(MB, AF, BF) do {                                                 \
        __builtin_amdgcn_s_setprio(1);                                          \
        _Pragma("unroll") for (int _m = 0; _m < 4; ++_m)                        \
        _Pragma("unroll") for (int _n = 0; _n < 4; ++_n)                        \
            acc[(MB) + _m][_n] = __builtin_amdgcn_mfma_f32_16x16x32_bf16(       \
                AF[_m], BF[_n], acc[(MB) + _m][_n], 0, 0, 0);                   \
        __builtin_amdgcn_s_setprio(0);                                          \
    } while (0)
#define LOADSC(t, SCA, SCB) do {                                                \
        _Pragma("unroll") for (int _m = 0; _m < 8; ++_m)                        \
            SCA[_m] = *(const uint16_t*)(As + sAoff[_m] + 2 * (t));             \
        _Pragma("unroll") for (int _n = 0; _n < 4; ++_n)                        \
            SCB[_n] = *(const uint16_t*)(Bs + sBoff[_n] + 2 * (t));             \
    } while (0)

    uint32_t scA[8], scB[4], scA2[8], scB2[4];

    // tile body: chunked b64 reads + counted lgkm; expansion under MFMA;
    // scales(t+1) + STAGE(t+1) issued early, drained by boundary vmcnt(0).
#define TILE_BODY(t, SCA, SCB, SCAN, SCBN) do {                                 \
        const int bb = ((t) & 1) * BUFBYTES;                                    \
        const bool pf = ((t) + 1) < nt;                                         \
        uint2 rb0[4], ra0[4], ra1[4], rb1[4], ra2[4], ra3[4];                   \
        _Pragma("unroll") for (int _n = 0; _n < 4; ++_n)                        \
            rb0[_n] = *(const uint2*)&lds[bb + boffk[_n][0]];                   \
        _Pragma("unroll") for (int _m = 0; _m < 4; ++_m)                        \
            ra0[_m] = *(const uint2*)&lds[bb + aoffk[_m][0]];                   \
        _Pragma("unroll") for (int _m = 0; _m < 4; ++_m)                        \
            ra1[_m] = *(const uint2*)&lds[bb + aoffk[4 + _m][0]];               \
        if (pf) { STAGE((t) + 1); LOADSC((t) + 1, SCAN, SCBN); }                \
        WAITL(4);                                                               \
        bf16x8 eA[4], eB[4];                                                    \
        _Pragma("unroll") for (int _n = 0; _n < 4; ++_n)                        \
            EXPAND(eB[_n], rb0[_n], SCB[_n] & 0xFFu);                           \
        _Pragma("unroll") for (int _m = 0; _m < 4; ++_m)                        \
            EXPAND(eA[_m], ra0[_m], SCA[_m] & 0xFFu);                           \
        MFMA_C(0, eA, eB);                                                      \
        _Pragma("unroll") for (int _n = 0; _n < 4; ++_n)                        \
            rb1[_n] = *(const uint2*)&lds[bb + boffk[_n][1]];                   \
        _Pragma("unroll") for (int _m = 0; _m < 4; ++_m)                        \
            ra2[_m] = *(const uint2*)&lds[bb + aoffk[_m][1]];                   \
        WAITL(8);                                                               \
        _Pragma("unroll") for (int _m = 0; _m < 4; ++_m)                        \
            EXPAND(eA[_m], ra1[_m], SCA[4 + _m] & 0xFFu);                       \
        MFMA_C(4, eA, eB);                                                      \
        _Pragma("unroll") for (int _m = 0; _m < 4; ++_m)                        \
            ra3[_m] = *(const uint2*)&lds[bb + aoffk[4 + _m][1]];               \
        WAITL(4);                                                               \
        _Pragma("unroll") for (int _n = 0; _n < 4; ++_n)                        \
            EXPAND(eB[_n], rb1[_n], (SCB[_n] >> 8) & 0xFFu);                    \
        _Pragma("unroll") for (int _m = 0; _m < 4; ++_m)                        \
            EXPAND(eA[_m], ra2[_m], (SCA[_m] >> 8) & 0xFFu);                    \
        MFMA_C(0, eA, eB);                                                      \
        WAITL(0);                                                               \
        _Pragma("unroll") for (int _m = 0; _m < 4; ++_m)                        \
            EXPAND(eA[_m], ra3[_m], (SCA[4 + _m] >> 8) & 0xFFu);                \
        MFMA_C(4, eA, eB);                                                      \
        asm volatile("s_waitcnt vmcnt(0)" ::: "memory");                        \
        __builtin_amdgcn_sched_barrier(0);                                      \
        __builtin_amdgcn_s_barrier();                                           \
        __builtin_amdgcn_sched_barrier(0);                                      \
    } while (0)

    // prologue
    STAGE(0);
    LOADSC(0, scA, scB);
    asm volatile("s_waitcnt vmcnt(0)" ::: "memory");
    __builtin_amdgcn_sched_barrier(0);
    __builtin_amdgcn_s_barrier();
    __builtin_amdgcn_sched_barrier(0);

    for (int tt = 0; tt < nt; tt += 2) {
        TILE_BODY(tt,     scA,  scB,  scA2, scB2);
        TILE_BODY(tt + 1, scA2, scB2, scA,  scB);
    }
#undef STAGE
#undef WAITL
#undef MFMA_C
#undef LOADSC
#undef TILE_BODY

    // epilogue: C/D layout col=lane&15, row=(lane>>4)*4+j (verified r1/r5-r12)
    const int qr = g * 4;
#pragma unroll
    for (int n = 0; n < 4; ++n) {
        int col = colBase + wn * 64 + n * 16 + f;
        float bv = bias[col];
#pragma unroll
        for (int m = 0; m < 8; ++m) {
            int r0 = rowBase + wm * 128 + m * 16 + qr;
#pragma unroll
            for (int j = 0; j < 4; ++j)
                C[(size_t)(r0 + j) * O + col] = acc[m][n][j] + bv;
        }
    }
}

extern "C" void kernel_launch(void* const* d_in, const int* in_sizes, int n_in,
                              void* d_out, int out_size, void* d_ws, size_t ws_size,
                              hipStream_t stream) {
    const float* x    = (const float*)d_in[0];
    const float* wgt  = (const float*)d_in[1];
    const float* bias = (const float*)d_in[2];
    float* out = (float*)d_out;

    const int D_OUT = in_sizes[2];             // 4096
    const int D_IN  = in_sizes[1] / D_OUT;     // 4096
    const int NROWS = in_sizes[0] / D_IN;      // 16384
    const int KB    = D_IN / 32;               // 128

    uint8_t* xq  = (uint8_t*)d_ws;                           // 64 MB
    uint8_t* wq  = xq + (size_t)NROWS * D_IN;                // 16 MB
    uint8_t* xs  = wq + (size_t)D_OUT * D_IN;                //  2 MB
    uint8_t* wsc = xs + (size_t)NROWS * KB;                  // 0.5 MB

    int nblkx = NROWS * KB;
    int nblkw = D_OUT * KB;
    mx_quant_fp8<<<dim3((nblkx + 255) / 256), dim3(256), 0, stream>>>(x, xq, xs, nblkx);
    mx_quant_fp8<<<dim3((nblkw + 255) / 256), dim3(256), 0, stream>>>(wgt, wq, wsc, nblkw);

    dim3 grid(D_OUT / BN, NROWS / BM);   // (16, 64) = 1024 blocks
    gemm_fp8c_bf16<<<grid, dim3(512), 0, stream>>>(xq, wq, xs, wsc, bias, out,
                                                   NROWS, D_IN, D_OUT);
}

// Round 15
// 1015.739 us; speedup vs baseline: 4.1131x; 2.6822x over previous
//
#include <hip/hip_runtime.h>
#include <hip/hip_bf16.h>
#include <stdint.h>

typedef __attribute__((ext_vector_type(8))) short bf16x8;
typedef __attribute__((ext_vector_type(4))) float f32x4;
typedef __attribute__((ext_vector_type(2))) float f32x2;
typedef __attribute__((ext_vector_type(4))) int i32x4;
typedef __attribute__((ext_vector_type(8))) unsigned short u16x8;

#define BM 256
#define BN 256
#define BKT 64
#define ALDS (BM * BKT)              // fp8 A tile: 16384
#define BLDS (BN * BKT * 2)          // bf16 B tile: 32768
#define BUFB (ALDS + BLDS)           // 49152; 2 buffers = 96 KB LDS

// ---------------- shared quant math (verified r1/r5-r14) --------------------
__device__ __forceinline__ float mx_qd_elem(float x, int e) {
    float xs = ldexpf(x, -e);
    xs = fminf(448.f, fmaxf(-448.f, xs));
    float a = fabsf(xs);
    float r;
    if (a < 0.015625f) {
        r = ldexpf(rintf(ldexpf(a, 9)), -9);
    } else {
        int E = (int)((__float_as_uint(a) >> 23) & 0xFF) - 127;
        r = ldexpf(rintf(ldexpf(a, 3 - E)), E - 3);
    }
    r = copysignf(r, xs);
    return ldexpf(r, e);
}

__device__ __forceinline__ uint8_t enc_e4m3(float x, int e) {
    float xs = ldexpf(x, -e);
    xs = fminf(448.f, fmaxf(-448.f, xs));
    float a = fabsf(xs);
    uint32_t sgn = (__float_as_uint(xs) >> 31) << 7;
    uint32_t mag;
    if (a < 0.015625f) {
        mag = (uint32_t)(int)rintf(ldexpf(a, 9));
    } else {
        int E = (int)((__float_as_uint(a) >> 23) & 0xFF) - 127;
        float q = ldexpf(rintf(ldexpf(a, 3 - E)), E - 3);
        uint32_t qb = __float_as_uint(q);
        int E2 = (int)((qb >> 23) & 0xFF) - 127;
        mag = ((uint32_t)(E2 + 7) << 3) | ((qb >> 20) & 7);
    }
    return (uint8_t)(sgn | mag);
}

// ---- B (weight) quant -> bf16 row-major (verified r1/r5-r12) ---------------
__global__ __launch_bounds__(256) void mx_quant_bf16(
    const float* __restrict__ in, uint16_t* __restrict__ out, int nblk) {
    int t = blockIdx.x * 256 + threadIdx.x;
    if (t >= nblk) return;
    const float4* p = (const float4*)(in + (size_t)t * 32);
    float v[32];
#pragma unroll
    for (int i = 0; i < 8; ++i) {
        float4 fv = p[i];
        v[4 * i + 0] = fv.x; v[4 * i + 1] = fv.y;
        v[4 * i + 2] = fv.z; v[4 * i + 3] = fv.w;
    }
    float amax = 0.f;
#pragma unroll
    for (int i = 0; i < 32; ++i) amax = fmaxf(amax, fabsf(v[i]));
    amax = fmaxf(amax, 1.17549435e-38f);
    int e = (int)((__float_as_uint(amax) >> 23) & 0xFF) - 127 - 8;
    unsigned short res[32];
#pragma unroll
    for (int i = 0; i < 32; ++i) {
        float d = mx_qd_elem(v[i], e);
        res[i] = (unsigned short)(__float_as_uint(d) >> 16);
    }
    u16x8* o = (u16x8*)(out + (size_t)t * 32);
#pragma unroll
    for (int j = 0; j < 4; ++j) {
        u16x8 pack;
#pragma unroll
        for (int i = 0; i < 8; ++i) pack[i] = res[8 * j + i];
        o[j] = pack;
    }
}

// ---- A (activation) quant -> fp8, 16B-chunk-transposed blocked layout ------
// A'[rb][kt][s][r][16B]: (rb,kt) 16KB block; chunk (s,r) = row rb*256+r,
// K-bytes [kt*64 + s*16, +16). Staging in the GEMM is then an identity copy.
// Scales: As'[kt][row] = u16 (kk0 byte, kk1 byte).
__global__ __launch_bounds__(256) void mx_quant_a_fp8(
    const float* __restrict__ in, uint8_t* __restrict__ qout,
    uint8_t* __restrict__ sout, int nrows, int K, int nblk) {
    int t = blockIdx.x * 256 + threadIdx.x;
    if (t >= nblk) return;
    const int KB = K / 32;
    int r   = t & 255;
    int tmp = t >> 8;
    int kb  = tmp % KB;
    int rb  = tmp / KB;
    int row = rb * 256 + r;

    const float4* p = (const float4*)(in + (size_t)row * K + kb * 32);
    float v[32];
#pragma unroll
    for (int i = 0; i < 8; ++i) {
        float4 fv = p[i];
        v[4 * i + 0] = fv.x; v[4 * i + 1] = fv.y;
        v[4 * i + 2] = fv.z; v[4 * i + 3] = fv.w;
    }
    float amax = 0.f;
#pragma unroll
    for (int i = 0; i < 32; ++i) amax = fmaxf(amax, fabsf(v[i]));
    amax = fmaxf(amax, 1.17549435e-38f);
    int e = (int)((__float_as_uint(amax) >> 23) & 0xFF) - 127 - 8;
    int E = e + 127;
    E = E < 1 ? 1 : (E > 254 ? 254 : E);
    sout[((size_t)(kb >> 1) * nrows + row) * 2 + (kb & 1)] = (uint8_t)E;

    uint8_t b[32];
#pragma unroll
    for (int i = 0; i < 32; ++i) b[i] = enc_e4m3(v[i], e);
    uint4 w0, w1;
    uint32_t* pw = (uint32_t*)&w0;
#pragma unroll
    for (int j = 0; j < 4; ++j)
        pw[j] = (uint32_t)b[4*j] | ((uint32_t)b[4*j+1] << 8) |
                ((uint32_t)b[4*j+2] << 16) | ((uint32_t)b[4*j+3] << 24);
    pw = (uint32_t*)&w1;
#pragma unroll
    for (int j = 0; j < 4; ++j)
        pw[j] = (uint32_t)b[16+4*j] | ((uint32_t)b[16+4*j+1] << 8) |
                ((uint32_t)b[16+4*j+2] << 16) | ((uint32_t)b[16+4*j+3] << 24);
    const int kt = kb >> 1, s0 = (kb & 1) * 2;
    uint8_t* base = qout + (((size_t)rb * (K / BKT) + kt) * 1024 + s0 * 256 + r) * 16;
    *(uint4*)(base)        = w0;   // slot s0
    *(uint4*)(base + 4096) = w1;   // slot s0+1
}

// ---------------- fp8 -> f32 pair decode (verified r14) ---------------------
#if __has_builtin(__builtin_amdgcn_cvt_pk_f32_fp8)
#define CVTPK(w, hi) __builtin_amdgcn_cvt_pk_f32_fp8((int)(w), hi)
#else
__device__ __forceinline__ f32x2 CVTPK_sw(uint32_t w, bool hi) {
    f32x2 r;
#pragma unroll
    for (int j = 0; j < 2; ++j) {
        uint32_t b = (w >> ((hi ? 2 : 0) + j) * 8) & 0xFF;
        uint32_t s = (b >> 7) << 31;
        uint32_t ex = (b >> 3) & 15, mn = b & 7;
        float v = ex ? __uint_as_float(((ex - 7 + 127) << 23) | (mn << 20))
                     : ldexpf((float)mn, -9);
        r[j] = __uint_as_float(s | __float_as_uint(v));
    }
    return r;
}
#define CVTPK(w, hi) CVTPK_sw((w), hi)
#endif

#define EXPAND(FR, RAW, SB) do {                                                \
        float _s = __uint_as_float((uint32_t)(SB) << 23);                       \
        f32x2 _p0 = CVTPK((RAW).x, false), _p1 = CVTPK((RAW).x, true);          \
        f32x2 _p2 = CVTPK((RAW).y, false), _p3 = CVTPK((RAW).y, true);          \
        i32x4 _d;                                                               \
        _d[0] = (int)__builtin_amdgcn_perm(__float_as_uint(_p0[1] * _s),        \
                    __float_as_uint(_p0[0] * _s), 0x07060302);                  \
        _d[1] = (int)__builtin_amdgcn_perm(__float_as_uint(_p1[1] * _s),        \
                    __float_as_uint(_p1[0] * _s), 0x07060302);                  \
        _d[2] = (int)__builtin_amdgcn_perm(__float_as_uint(_p2[1] * _s),        \
                    __float_as_uint(_p2[0] * _s), 0x07060302);                  \
        _d[3] = (int)__builtin_amdgcn_perm(__float_as_uint(_p3[1] * _s),        \
                    __float_as_uint(_p3[0] * _s), 0x07060302);                  \
        FR = *(const bf16x8*)&_d;                                               \
    } while (0)

// ---------------- GEMM: A fp8-LDS (chunk-transposed) x B bf16-LDS -----------
#define GLOAD(srcp, ldsoff)                                                     \
    __builtin_amdgcn_global_load_lds(                                           \
        (const __attribute__((address_space(1))) void*)(srcp),                  \
        (__attribute__((address_space(3))) void*)&lds[ldsoff], 16, 0, 0)

typedef const __attribute__((address_space(1))) uint16_t* gptr_u16;

__global__ __launch_bounds__(512, 2) void gemm_afp8_bf16(
    const uint8_t* __restrict__ A, const uint16_t* __restrict__ B,
    const uint8_t* __restrict__ As, const float* __restrict__ bias,
    float* __restrict__ C, int Nrows, int K, int O) {
    __shared__ __align__(16) uint8_t lds[2 * BUFB];   // 96 KB

    const int tid  = threadIdx.x;
    const int lane = tid & 63;
    const int w    = tid >> 6;
    const int f    = lane & 15, g = lane >> 4;
    const int wm   = w >> 2,    wn = w & 3;     // 2M x 4N

    // r12 column-chunked snake XCD swizzle (nwg=1024, bijective)
    const int flat = blockIdx.y * gridDim.x + blockIdx.x;
    const int xcd  = flat & 7;
    const int loc  = flat >> 3;
    const int bxl  = loc >> 6;
    const int byl  = loc & 63;
    const int by   = bxl ? (63 - byl) : byl;
    const int bx   = xcd * 2 + bxl;
    const int rowBase = by * BM, colBase = bx * BN;

    const int sld = tid * 16;
    // A staging: identity copy from A' block (by, t): 2 x 8KB rounds
    const uint8_t* gA = A + (size_t)by * (K / BKT) * 16384 + sld;
    // B staging: r12-verified rows + inverse-swizzled source col
    const int sri  = tid >> 3;
    const int sscB = ((tid & 7) * 16) ^ ((sri & 7) << 4);
    const size_t K2 = (size_t)K * 2;
    const uint8_t* gBr[4];
#pragma unroll
    for (int j = 0; j < 4; ++j)
        gBr[j] = (const uint8_t*)B + (size_t)(colBase + j * 64 + sri) * K2 + sscB;

#define STAGE(t) do {                                                           \
        const int _buf = ((t) & 1) * BUFB;                                      \
        GLOAD(gA + (size_t)(t) * 16384,        _buf + sld);                     \
        GLOAD(gA + (size_t)(t) * 16384 + 8192, _buf + 8192 + sld);              \
        const size_t _kb = (size_t)(t) * (BKT * 2);                             \
        _Pragma("unroll")                                                       \
        for (int _j = 0; _j < 4; ++_j)                                          \
            GLOAD(gBr[_j] + _kb, _buf + ALDS + _j * 8192 + sld);                \
    } while (0)

    // A frag bases: addr = bb + (kk*2 + g>>1)*4096 + (wm*128+f)*16 + (g&1)*8 + m*256
    const int aBase0 = (g >> 1) * 4096 + (wm * 128 + f) * 16 + (g & 1) * 8;
    const int aBase1 = aBase0 + 8192;
    // B frag bases (r12-verified swizzle): + n*2048
    const int bRow   = (wn * 64 + f) * 128;
    const int bBase0 = ALDS + bRow + ((g * 16) ^ ((f & 7) << 4));
    const int bBase1 = ALDS + bRow + (((64 + g * 16)) ^ ((f & 7) << 4));
    // A scale row base
    const int aSrow  = rowBase + wm * 128 + f;

    f32x4 acc[8][4];
#pragma unroll
    for (int m = 0; m < 8; ++m)
#pragma unroll
        for (int n = 0; n < 4; ++n)
#pragma unroll
            for (int j = 0; j < 4; ++j) acc[m][n][j] = 0.f;

    const int nt = K / BKT;   // 64 (even)

#define WAITL(N) do {                                                           \
        asm volatile("s_waitcnt lgkmcnt(" #N ")" ::: "memory");                 \
        __builtin_amdgcn_sched_barrier(0);                                      \
    } while (0)
#define MFMA_C(MB, AF, BF) do {                                                 \
        __builtin_amdgcn_s_setprio(1);                                          \
        _Pragma("unroll") for (int _m = 0; _m < 4; ++_m)                        \
        _Pragma("unroll") for (int _n = 0; _n < 4; ++_n)                        \
            acc[(MB) + _m][_n] = __builtin_amdgcn_mfma_f32_16x16x32_bf16(       \
                AF[_m], BF[_n], acc[(MB) + _m][_n], 0, 0, 0);                   \
        __builtin_amdgcn_s_setprio(0);                                          \
    } while (0)
// address_space(1) cast -> guaranteed global_load (vmcnt-only; ledger safe)
#define LOADSC(t, SC) do {                                                      \
        const uint8_t* _p = As + ((size_t)(t) * Nrows + aSrow) * 2;             \
        _Pragma("unroll") for (int _m = 0; _m < 8; ++_m)                        \
            SC[_m] = (uint32_t)*(gptr_u16)(_p + _m * 32);                       \
    } while (0)

    uint32_t scA[8], scN[8];
    bf16x8 bB0[4], bB1[4], eA[4];
    uint2 raw0[4], raw1[4];

    // Ledger per wave (in-order DS queue; mixed b64/b128 each count 1):
    //  bB0(4) raw0(4) raw1(4) | STAGE+LOADSC(vm) | L(4): bB0+raw0 done
    //  MFMA1 | bB1(4) raw0'(4) | L(8): raw1 done | MFMA2 | raw1'(4)
    //  L(4): bB1+raw0' done | MFMA3 | L(0): raw1' done | MFMA4 | vm(0) bar
#define TILE_BODY(t, SCC, SCN_) do {                                            \
        const int bb = ((t) & 1) * BUFB;                                        \
        const bool pf = ((t) + 1) < nt;                                         \
        _Pragma("unroll") for (int _n = 0; _n < 4; ++_n)                        \
            bB0[_n] = *(const bf16x8*)&lds[bb + bBase0 + _n * 2048];            \
        _Pragma("unroll") for (int _m = 0; _m < 4; ++_m)                        \
            raw0[_m] = *(const uint2*)&lds[bb + aBase0 + _m * 256];             \
        _Pragma("unroll") for (int _m = 0; _m < 4; ++_m)                        \
            raw1[_m] = *(const uint2*)&lds[bb + aBase0 + 1024 + _m * 256];      \
        if (pf) { STAGE((t) + 1); LOADSC((t) + 1, SCN_); }                      \
        WAITL(4);                                                               \
        _Pragma("unroll") for (int _m = 0; _m < 4; ++_m)                        \
            EXPAND(eA[_m], raw0[_m], SCC[_m] & 0xFFu);                          \
        MFMA_C(0, eA, bB0);                                                     \
        _Pragma("unroll") for (int _n = 0; _n < 4; ++_n)                        \
            bB1[_n] = *(const bf16x8*)&lds[bb + bBase1 + _n * 2048];            \
        _Pragma("unroll") for (int _m = 0; _m < 4; ++_m)                        \
            raw0[_m] = *(const uint2*)&lds[bb + aBase1 + _m * 256];             \
        WAITL(8);                                                               \
        _Pragma("unroll") for (int _m = 0; _m < 4; ++_m)                        \
            EXPAND(eA[_m], raw1[_m], SCC[4 + _m] & 0xFFu);                      \
        MFMA_C(4, eA, bB0);                                                     \
        _Pragma("unroll") for (int _m = 0; _m < 4; ++_m)                        \
            raw1[_m] = *(const uint2*)&lds[bb + aBase1 + 1024 + _m * 256];      \
        WAITL(4);                                                               \
        _Pragma("unroll") for (int _m = 0; _m < 4; ++_m)                        \
            EXPAND(eA[_m], raw0[_m], (SCC[_m] >> 8) & 0xFFu);                   \
        MFMA_C(0, eA, bB1);                                                     \
        WAITL(0);                                                               \
        _Pragma("unroll") for (int _m = 0; _m < 4; ++_m)                        \
            EXPAND(eA[_m], raw1[_m], (SCC[4 + _m] >> 8) & 0xFFu);               \
        MFMA_C(4, eA, bB1);                                                     \
        asm volatile("s_waitcnt vmcnt(0)" ::: "memory");                        \
        __builtin_amdgcn_sched_barrier(0);                                      \
        __builtin_amdgcn_s_barrier();                                           \
        __builtin_amdgcn_sched_barrier(0);                                      \
    } while (0)

    // prologue
    STAGE(0);
    LOADSC(0, scA);
    asm volatile("s_waitcnt vmcnt(0)" ::: "memory");
    __builtin_amdgcn_sched_barrier(0);
    __builtin_amdgcn_s_barrier();
    __builtin_amdgcn_sched_barrier(0);

    for (int tt = 0; tt < nt; tt += 2) {
        TILE_BODY(tt,     scA, scN);
        TILE_BODY(tt + 1, scN, scA);
    }
#undef STAGE
#undef WAITL
#undef MFMA_C
#undef LOADSC
#undef TILE_BODY

    // epilogue: C/D layout col=lane&15, row=(lane>>4)*4+j (verified r1/r5-r14)
    const int qr = g * 4;
#pragma unroll
    for (int n = 0; n < 4; ++n) {
        int col = colBase + wn * 64 + n * 16 + f;
        float bv = bias[col];
#pragma unroll
        for (int m = 0; m < 8; ++m) {
            int r0 = rowBase + wm * 128 + m * 16 + qr;
#pragma unroll
            for (int j = 0; j < 4; ++j)
                C[(size_t)(r0 + j) * O + col] = acc[m][n][j] + bv;
        }
    }
}

extern "C" void kernel_launch(void* const* d_in, const int* in_sizes, int n_in,
                              void* d_out, int out_size, void* d_ws, size_t ws_size,
                              hipStream_t stream) {
    const float* x    = (const float*)d_in[0];
    const float* wgt  = (const float*)d_in[1];
    const float* bias = (const float*)d_in[2];
    float* out = (float*)d_out;

    const int D_OUT = in_sizes[2];             // 4096
    const int D_IN  = in_sizes[1] / D_OUT;     // 4096
    const int NROWS = in_sizes[0] / D_IN;      // 16384
    const int KB    = D_IN / 32;               // 128

    uint8_t*  xq = (uint8_t*)d_ws;                                // A' fp8: 64 MB
    uint8_t*  xs = xq + (size_t)NROWS * D_IN;                     // As': 2 MB
    uint16_t* wq = (uint16_t*)(xs + (size_t)(D_IN / BKT) * NROWS * 2);  // B bf16: 32 MB

    int nblkx = NROWS * KB;
    int nblkw = D_OUT * KB;
    mx_quant_a_fp8<<<dim3((nblkx + 255) / 256), dim3(256), 0, stream>>>(
        x, xq, xs, NROWS, D_IN, nblkx);
    mx_quant_bf16<<<dim3((nblkw + 255) / 256), dim3(256), 0, stream>>>(
        wgt, wq, nblkw);

    dim3 grid(D_OUT / BN, NROWS / BM);   // (16, 64) = 1024 blocks
    gemm_afp8_bf16<<<grid, dim3(512), 0, stream>>>(xq, wq, xs, bias, out,
                                                   NROWS, D_IN, D_OUT);
}